// Round 7
// baseline (1725.112 us; speedup 1.0000x reference)
//
#include <hip/hip_runtime.h>

typedef int i32x4 __attribute__((ext_vector_type(4)));

static constexpr int M_TOK = 16384;       // B*S
static constexpr int D_IN  = 2048;
static constexpr int H_FF  = 5632;
static constexpr int NW    = H_FF * D_IN; // 11534336

#define MFMA_I8 __builtin_amdgcn_mfma_i32_16x16x64_i8

__device__ __forceinline__ void async16(const void* g, void* l) {
    __builtin_amdgcn_global_load_lds((__attribute__((address_space(1))) void*)g,
                                     (__attribute__((address_space(3))) void*)l,
                                     16, 0, 0);
}

// raw workgroup barrier WITHOUT the vmcnt(0)/lgkmcnt(0) drain __syncthreads emits.
__device__ __forceinline__ void sbar() {
    asm volatile("" ::: "memory");
    __builtin_amdgcn_s_barrier();
    asm volatile("" ::: "memory");
}
// counted waits; sched_barrier(0) after lgkm keeps dependent MFMAs below the wait (rule 18)
#define WAIT_LGKM(n) { asm volatile("s_waitcnt lgkmcnt(" #n ")" ::: "memory"); \
                       __builtin_amdgcn_sched_barrier(0); }
#define WAIT_VM(n)   { asm volatile("s_waitcnt vmcnt(" #n ")" ::: "memory"); }

// ---------------- weight abs-mean reduction, FP64 accumulate ----------------
__global__ void absum_partial(const float4* __restrict__ w, int n4, double* __restrict__ part) {
    __shared__ double s[256];
    const int t = threadIdx.x;
    double acc = 0.0;
    for (int i = blockIdx.x * 256 + t; i < n4; i += gridDim.x * 256) {
        float4 v = w[i];
        acc += fabs((double)v.x) + fabs((double)v.y) + fabs((double)v.z) + fabs((double)v.w);
    }
    s[t] = acc;
    __syncthreads();
    for (int o = 128; o > 0; o >>= 1) {
        if (t < o) s[t] += s[t + o];
        __syncthreads();
    }
    if (t == 0) part[blockIdx.x] = s[0];
}

__global__ void finalize_scales(const double* __restrict__ parts, double* __restrict__ scales,
                                int nblocks, double inv_n) {
    const int t = threadIdx.x;
    if (t < 3) {
        const double* p = parts + t * nblocks;
        double s = 0.0;
        for (int i = 0; i < nblocks; ++i) s += p[i];
        double c = fmax(s * inv_n, 1e-5);   // clip(mean|w|, EPS)
        scales[t * 2]     = 1.0 / c;        // quantization scale (fp64)
        scales[t * 2 + 1] = c;              // dequant coeff (fp64)
    }
}

// ---------------- weight ternarization (FP64 rounding decision) -> int8 {-1,0,1} ----------
__global__ void quant_w_kernel(const float4* __restrict__ w, unsigned int* __restrict__ tw,
                               const double* __restrict__ scales, int idx, int n4) {
    const double s = scales[idx * 2];
    const int stride = gridDim.x * blockDim.x;
    for (int i = blockIdx.x * blockDim.x + threadIdx.x; i < n4; i += stride) {
        float4 v = w[i];
        int q0 = (int)fmin(fmax(rint((double)v.x * s), -1.0), 1.0);
        int q1 = (int)fmin(fmax(rint((double)v.y * s), -1.0), 1.0);
        int q2 = (int)fmin(fmax(rint((double)v.z * s), -1.0), 1.0);
        int q3 = (int)fmin(fmax(rint((double)v.w * s), -1.0), 1.0);
        tw[i] = (unsigned int)((q0 & 255) | ((q1 & 255) << 8) |
                               ((q2 & 255) << 16) | ((q3 & 255) << 24));
    }
}

// ---------------- x: rmsnorm + int8 absmax quant, FP64 stats & rounding ----------------
__global__ void quant_x_kernel(const float* __restrict__ x, signed char* __restrict__ qx,
                               double* __restrict__ cx) {
    __shared__ double ssum[256];
    __shared__ float  smax[256];
    const int token = blockIdx.x;
    const int t = threadIdx.x;
    const float4* xr = (const float4*)(x + (size_t)token * D_IN);
    float4 v0 = xr[t];
    float4 v1 = xr[t + 256];
    double ss = (double)v0.x*v0.x + (double)v0.y*v0.y + (double)v0.z*v0.z + (double)v0.w*v0.w
              + (double)v1.x*v1.x + (double)v1.y*v1.y + (double)v1.z*v1.z + (double)v1.w*v1.w;
    float mx = fmaxf(fmaxf(fmaxf(fabsf(v0.x), fabsf(v0.y)), fmaxf(fabsf(v0.z), fabsf(v0.w))),
                     fmaxf(fmaxf(fabsf(v1.x), fabsf(v1.y)), fmaxf(fabsf(v1.z), fabsf(v1.w))));
    ssum[t] = ss; smax[t] = mx;
    __syncthreads();
    for (int o = 128; o > 0; o >>= 1) {
        if (t < o) { ssum[t] += ssum[t + o]; smax[t] = fmaxf(smax[t], smax[t + o]); }
        __syncthreads();
    }
    const double ms    = ssum[0] * (1.0 / (double)D_IN);
    const double r     = 1.0 / sqrt(ms + 1e-6);
    const double den   = fmax((double)smax[0] * r, 1e-5);   // clip(max|xn|, EPS)
    const double scale = 127.0 / den;
    if (t == 0) cx[token] = den * (1.0 / 127.0);

    int q0 = (int)fmin(fmax(rint(((double)v0.x * r) * scale), -128.0), 127.0);
    int q1 = (int)fmin(fmax(rint(((double)v0.y * r) * scale), -128.0), 127.0);
    int q2 = (int)fmin(fmax(rint(((double)v0.z * r) * scale), -128.0), 127.0);
    int q3 = (int)fmin(fmax(rint(((double)v0.w * r) * scale), -128.0), 127.0);
    int q4 = (int)fmin(fmax(rint(((double)v1.x * r) * scale), -128.0), 127.0);
    int q5 = (int)fmin(fmax(rint(((double)v1.y * r) * scale), -128.0), 127.0);
    int q6 = (int)fmin(fmax(rint(((double)v1.z * r) * scale), -128.0), 127.0);
    int q7 = (int)fmin(fmax(rint(((double)v1.w * r) * scale), -128.0), 127.0);
    unsigned int* qr = (unsigned int*)(qx + (size_t)token * D_IN);
    qr[t]       = (unsigned int)((q0 & 255) | ((q1 & 255) << 8) | ((q2 & 255) << 16) | ((q3 & 255) << 24));
    qr[t + 256] = (unsigned int)((q4 & 255) | ((q5 & 255) << 8) | ((q6 & 255) << 16) | ((q7 & 255) << 24));
}

// ---------------- h: rmsnorm + quant IN-PLACE per token (int8 overlay), FP64 stats --------
__global__ void quant_h_kernel(float* __restrict__ h, double* __restrict__ ch) {
    __shared__ double ssum[256];
    __shared__ float  smax[256];
    const int token = blockIdx.x;
    const int t = threadIdx.x;
    float* hr = h + (size_t)token * H_FF;
    const float2* h2 = (const float2*)hr;
    float2 vals[11];                      // 5632 floats = 2816 float2 = 256*11
    double ss = 0.0;
    float mx = 0.f;
#pragma unroll
    for (int k = 0; k < 11; ++k) {
        float2 v = h2[t + 256 * k];
        vals[k] = v;
        ss += (double)v.x * (double)v.x + (double)v.y * (double)v.y;
        mx = fmaxf(mx, fmaxf(fabsf(v.x), fabsf(v.y)));
    }
    ssum[t] = ss; smax[t] = mx;
    __syncthreads();
    for (int o = 128; o > 0; o >>= 1) {
        if (t < o) { ssum[t] += ssum[t + o]; smax[t] = fmaxf(smax[t], smax[t + o]); }
        __syncthreads();
    }
    const double ms    = ssum[0] * (1.0 / (double)H_FF);
    const double r     = 1.0 / sqrt(ms + 1e-6);
    const double den   = fmax((double)smax[0] * r, 1e-5);
    const double scale = 127.0 / den;
    if (t == 0) ch[token] = den * (1.0 / 127.0);
    unsigned short* qr = (unsigned short*)hr;   // in-place overlay, same token row
#pragma unroll
    for (int k = 0; k < 11; ++k) {
        int a = (int)fmin(fmax(rint(((double)vals[k].x * r) * scale), -128.0), 127.0);
        int b = (int)fmin(fmax(rint(((double)vals[k].y * r) * scale), -128.0), 127.0);
        qr[t + 256 * k] = (unsigned short)((a & 255) | ((b & 255) << 8));
    }
}

// GEMM structure (v7): A staged in LDS (3 x 16KB bufs, XOR-swizzled, conflict-free);
// B fragments loaded DIRECTLY from global (L2/L1) into registers, double-buffered one
// tile ahead. This removes B's staging-write + 4x-duplicated ds_read from the shared
// per-CU LDS pipe (round-6 analysis: LDS pipe 65% busy was the binder; MFMA only 44%).
// vmcnt per tile: issue [B(kt+1) x4, A-stage(kt+2) x2]; end-of-tile WAIT_VM(2) drains
// B(kt+1)+A(kt+1), keeps A(kt+2) in flight. One barrier per tile guards A buf recycle.

// ---------------- fused GEMM1+2, i8 MFMA, B-from-global pipeline --------------------------
// BM=256, BN=64, BK=64, 512 threads (8 waves: 4M x 2N, 64x32 per wave per gemm).
__global__ void __launch_bounds__(512, 4) gemm12_kernel(
    const signed char* __restrict__ qx,
    const signed char* __restrict__ tw1,   // tw2 = tw1 + NW (contiguous in workspace)
    const double* __restrict__ cx,
    const double* __restrict__ scales,
    float* __restrict__ h)
{
    __shared__ __attribute__((aligned(16))) signed char lds[3][16384];   // A only

    const int t = threadIdx.x;
    // grid 5632 = 8 XCD x 704 (= 11 bn x 64 bm); bm-fastest within chunk so the ~64
    // concurrent blocks/XCD span ~8 bn values -> B working set ~2MB, L2-resident.
    const int swz = (blockIdx.x & 7) * 704 + (blockIdx.x >> 3);
    const int bm  = swz & 63;    // 0..63
    const int bn  = swz >> 6;    // 0..87

    const int srow = t >> 2;           // 0..127
    const int scol = (((t & 3) ^ ((t >> 3) & 3)) << 4);   // inverse-swizzled global slot
    const signed char* gA = qx + (size_t)(bm * 256 + srow) * D_IN + scol;
    const size_t arstep = (size_t)128 * D_IN;
    const int l16 = t * 16;

    const int lane = t & 63;
    const int wv = t >> 6;        // 0..7
    const int wm = wv & 3;        // 4 M-waves (64 rows each)
    const int wn = wv >> 2;       // 2 N-waves (32 cols each per gemm)
    const int lm = lane & 15;
    const int kg = lane >> 4;
    const int koff  = ((kg ^ ((lm >> 1) & 3)) << 4);      // swizzled read slot
    const int abase = (wm * 64 + lm) * 64 + koff;         // + i*1024, i=0..3

    // B fragment base: lane reads col (wn*32 + j*16 + lm), bytes k=kg*16..+15 of tile kt
    const signed char* gB1 = tw1 + (size_t)(bn * 64 + wn * 32 + lm) * D_IN + kg * 16;

    const i32x4 izero = {0, 0, 0, 0};
    i32x4 acc1[4][2], acc2[4][2];
#pragma unroll
    for (int i = 0; i < 4; ++i)
#pragma unroll
        for (int j = 0; j < 2; ++j) { acc1[i][j] = izero; acc2[i][j] = izero; }

    i32x4 bA[4], bB[4];   // [0..1]=B1 j=0,1 ; [2..3]=B2 j=0,1

    constexpr int NT = D_IN / 64;   // 32 K-tiles

#define STAGE_A12(buf, kt) { const int go = (kt) * 64;                       \
        async16(gA + go,          &lds[buf][l16]);                           \
        async16(gA + arstep + go, &lds[buf][8192 + l16]); }
#define LOADB12(R, kt) { const int go = (kt) * 64;                           \
        R[0] = *(const i32x4*)(gB1 + go);                                    \
        R[1] = *(const i32x4*)(gB1 + 16 * D_IN + go);                        \
        R[2] = *(const i32x4*)(gB1 + NW + go);                               \
        R[3] = *(const i32x4*)(gB1 + NW + 16 * D_IN + go); }
#define TILE12(kt, RC, RN) {                                                 \
        if ((kt) + 1 < NT) { LOADB12(RN, (kt) + 1); }                        \
        __builtin_amdgcn_sched_barrier(0);                                   \
        if ((kt) + 2 < NT) { STAGE_A12(((kt) + 2) % 3, (kt) + 2); }          \
        __builtin_amdgcn_sched_barrier(0);                                   \
        const int cb = (kt) % 3;                                             \
        i32x4 a[4];                                                          \
        _Pragma("unroll") for (int i = 0; i < 4; ++i)                        \
            a[i] = *(const i32x4*)&lds[cb][abase + i * 1024];                \
        WAIT_LGKM(0);                                                        \
        __builtin_amdgcn_s_setprio(1);                                       \
        _Pragma("unroll") for (int i = 0; i < 4; ++i) {                      \
            acc1[i][0] = MFMA_I8(a[i], RC[0], acc1[i][0], 0, 0, 0);          \
            acc1[i][1] = MFMA_I8(a[i], RC[1], acc1[i][1], 0, 0, 0);          \
            acc2[i][0] = MFMA_I8(a[i], RC[2], acc2[i][0], 0, 0, 0);          \
            acc2[i][1] = MFMA_I8(a[i], RC[3], acc2[i][1], 0, 0, 0); }        \
        __builtin_amdgcn_s_setprio(0);                                       \
        if ((kt) + 2 < NT) { WAIT_VM(2); } else { WAIT_VM(0); }              \
        sbar(); }

    // prologue: FIFO [A0(2), B0(4), A1(2)] -> WAIT_VM(2) drains A0+B0, keeps A1
    STAGE_A12(0, 0);
    __builtin_amdgcn_sched_barrier(0);
    LOADB12(bA, 0);
    __builtin_amdgcn_sched_barrier(0);
    STAGE_A12(1, 1);
    WAIT_VM(2);
    sbar();

    for (int kt = 0; kt < NT; kt += 2) {
        TILE12(kt,     bA, bB);
        TILE12(kt + 1, bB, bA);
    }
#undef STAGE_A12
#undef LOADB12
#undef TILE12

    // epilogue: exact int accumulators, FP64 scale products, fp32 silu
    const double cw1 = scales[1];
    const double cw2 = scales[3];
#pragma unroll
    for (int i = 0; i < 4; ++i) {
#pragma unroll
        for (int v = 0; v < 4; ++v) {
            const int row = bm * 256 + wm * 64 + i * 16 + kg * 4 + v;
            const double c  = cx[row];
            const double s1 = c * cw1, s2 = c * cw2;
            float* hp = h + (size_t)row * H_FF + bn * 64 + wn * 32 + lm;
#pragma unroll
            for (int j = 0; j < 2; ++j) {
                float g  = (float)((double)acc1[i][j][v] * s1);
                float u  = (float)((double)acc2[i][j][v] * s2);
                float sg = g / (1.0f + expf(-g));   // silu
                hp[j * 16] = sg * u;
            }
        }
    }
}

// ---------------- GEMM3: i8 h-overlay x ternary w3, same B-from-global pipeline -----------
// BM=256, BN=128, BK=64, 512 threads (8 waves: 4M x 2N, 64x64 per wave).
__global__ void __launch_bounds__(512, 4) gemm3_kernel(
    const signed char* __restrict__ qh,
    const signed char* __restrict__ tw3,
    const double* __restrict__ ch,
    const double* __restrict__ scales,
    float* __restrict__ out)
{
    __shared__ __attribute__((aligned(16))) signed char lds[3][16384];   // A only

    const int t = threadIdx.x;
    // grid 1024 = 8 XCD x 128 (= 2 bn x 64 bm); bm-fastest
    const int swz = (blockIdx.x & 7) * 128 + (blockIdx.x >> 3);
    const int bm  = swz & 63;    // 0..63
    const int bn  = swz >> 6;    // 0..15

    const int srow = t >> 2;     // 0..127
    const int scol = (((t & 3) ^ ((t >> 3) & 3)) << 4);
    const size_t qh_stride = (size_t)4 * H_FF;   // bytes per token row (fp32 overlay)
    const signed char* gA = qh + (size_t)(bm * 256 + srow) * qh_stride + scol;
    const size_t arstep = (size_t)128 * qh_stride;
    const int l16 = t * 16;

    const int lane = t & 63;
    const int wv = t >> 6;
    const int wm = wv & 3;        // 4 M-waves (64 rows each)
    const int wn = wv >> 2;       // 2 N-waves (64 cols each)
    const int lm = lane & 15;
    const int kg = lane >> 4;
    const int koff  = ((kg ^ ((lm >> 1) & 3)) << 4);
    const int abase = (wm * 64 + lm) * 64 + koff;          // + i*1024, i=0..3

    const signed char* gB3 = tw3 + (size_t)(bn * 128 + wn * 64 + lm) * H_FF + kg * 16;

    const i32x4 izero = {0, 0, 0, 0};
    i32x4 acc[4][4];
#pragma unroll
    for (int i = 0; i < 4; ++i)
#pragma unroll
        for (int j = 0; j < 4; ++j) acc[i][j] = izero;

    i32x4 bA[4], bB[4];

    constexpr int NT = H_FF / 64;   // 88 K-tiles

#define STAGE_A3(buf, kt) { const int go = (kt) * 64;                        \
        async16(gA + go,          &lds[buf][l16]);                           \
        async16(gA + arstep + go, &lds[buf][8192 + l16]); }
#define LOADB3(R, kt) { const int go = (kt) * 64;                            \
        R[0] = *(const i32x4*)(gB3 + go);                                    \
        R[1] = *(const i32x4*)(gB3 + 16 * H_FF + go);                        \
        R[2] = *(const i32x4*)(gB3 + 32 * H_FF + go);                        \
        R[3] = *(const i32x4*)(gB3 + 48 * H_FF + go); }
#define TILE3(kt, RC, RN) {                                                  \
        if ((kt) + 1 < NT) { LOADB3(RN, (kt) + 1); }                         \
        __builtin_amdgcn_sched_barrier(0);                                   \
        if ((kt) + 2 < NT) { STAGE_A3(((kt) + 2) % 3, (kt) + 2); }           \
        __builtin_amdgcn_sched_barrier(0);                                   \
        const int cb = (kt) % 3;                                             \
        i32x4 a[4];                                                          \
        _Pragma("unroll") for (int i = 0; i < 4; ++i)                        \
            a[i] = *(const i32x4*)&lds[cb][abase + i * 1024];                \
        WAIT_LGKM(0);                                                        \
        __builtin_amdgcn_s_setprio(1);                                       \
        _Pragma("unroll") for (int i = 0; i < 4; ++i)                        \
        _Pragma("unroll") for (int j = 0; j < 4; ++j)                        \
            acc[i][j] = MFMA_I8(a[i], RC[j], acc[i][j], 0, 0, 0);            \
        __builtin_amdgcn_s_setprio(0);                                       \
        if ((kt) + 2 < NT) { WAIT_VM(2); } else { WAIT_VM(0); }              \
        sbar(); }

    STAGE_A3(0, 0);
    __builtin_amdgcn_sched_barrier(0);
    LOADB3(bA, 0);
    __builtin_amdgcn_sched_barrier(0);
    STAGE_A3(1, 1);
    WAIT_VM(2);
    sbar();

    for (int kt = 0; kt < NT; kt += 2) {
        TILE3(kt,     bA, bB);
        TILE3(kt + 1, bB, bA);
    }
#undef STAGE_A3
#undef LOADB3
#undef TILE3

    const double cw3 = scales[5];
#pragma unroll
    for (int i = 0; i < 4; ++i) {
#pragma unroll
        for (int v = 0; v < 4; ++v) {
            const int row = bm * 256 + wm * 64 + i * 16 + kg * 4 + v;
            const double sc = ch[row] * cw3;
            float* op = out + (size_t)row * D_IN + bn * 128 + wn * 64 + lm;
#pragma unroll
            for (int j = 0; j < 4; ++j) op[j * 16] = (float)((double)acc[i][j][v] * sc);
        }
    }
}

// ---------------- launch ----------------
extern "C" void kernel_launch(void* const* d_in, const int* in_sizes, int n_in,
                              void* d_out, int out_size, void* d_ws, size_t ws_size,
                              hipStream_t stream) {
    const float* x  = (const float*)d_in[0];
    const float* w1 = (const float*)d_in[1];
    const float* w2 = (const float*)d_in[2];
    const float* w3 = (const float*)d_in[3];

    char* ws = (char*)d_ws;
    // workspace layout (bytes, 256-aligned); total = 437,544,960
    double*      scales = (double*)(ws + 0);           // 6 d
    double*      parts  = (double*)(ws + 256);         // 3*1024 d = 24576 B
    double*      cx     = (double*)(ws + 25088);       // 16384 d = 131072 B
    double*      ch     = (double*)(ws + 156416);      // 16384 d = 131072 B
    signed char* tw1    = (signed char*)(ws + 287744);      // 11,534,336 B
    signed char* tw2    = (signed char*)(ws + 11822080);    // = tw1 + NW (contiguous!)
    signed char* tw3    = (signed char*)(ws + 23356416);    // 11,534,336 B
    float*       hb     = (float*)(ws + 34891520);          // 369,098,752 B (int8 qh overlays in-place)
    signed char* qx     = (signed char*)(ws + 403990528);   // 33,554,432 B

    absum_partial<<<1024, 256, 0, stream>>>((const float4*)w1, NW / 4, parts);
    absum_partial<<<1024, 256, 0, stream>>>((const float4*)w2, NW / 4, parts + 1024);
    absum_partial<<<1024, 256, 0, stream>>>((const float4*)w3, NW / 4, parts + 2048);
    finalize_scales<<<1, 64, 0, stream>>>(parts, scales, 1024, 1.0 / (double)NW);
    quant_w_kernel<<<2048, 256, 0, stream>>>((const float4*)w1, (unsigned int*)tw1, scales, 0, NW / 4);
    quant_w_kernel<<<2048, 256, 0, stream>>>((const float4*)w2, (unsigned int*)tw2, scales, 1, NW / 4);
    quant_w_kernel<<<2048, 256, 0, stream>>>((const float4*)w3, (unsigned int*)tw3, scales, 2, NW / 4);
    quant_x_kernel<<<M_TOK, 256, 0, stream>>>(x, qx, cx);
    gemm12_kernel<<<5632, 512, 0, stream>>>(qx, tw1, cx, scales, hb);
    quant_h_kernel<<<M_TOK, 256, 0, stream>>>(hb, ch);
    gemm3_kernel<<<1024, 512, 0, stream>>>((const signed char*)hb, tw3, ch, scales, (float*)d_out);
}

// Round 8
// 1196.460 us; speedup vs baseline: 1.4418x; 1.4418x over previous
//
#include <hip/hip_runtime.h>

typedef int i32x4 __attribute__((ext_vector_type(4)));

static constexpr int M_TOK = 16384;       // B*S
static constexpr int D_IN  = 2048;
static constexpr int H_FF  = 5632;
static constexpr int NW    = H_FF * D_IN; // 11534336

#define MFMA_I8 __builtin_amdgcn_mfma_i32_16x16x64_i8

__device__ __forceinline__ void async16(const void* g, void* l) {
    __builtin_amdgcn_global_load_lds((__attribute__((address_space(1))) void*)g,
                                     (__attribute__((address_space(3))) void*)l,
                                     16, 0, 0);
}

// raw workgroup barrier WITHOUT the vmcnt(0)/lgkmcnt(0) drain __syncthreads emits.
__device__ __forceinline__ void sbar() {
    asm volatile("" ::: "memory");
    __builtin_amdgcn_s_barrier();
    asm volatile("" ::: "memory");
}
#define WAIT_LGKM(n) { asm volatile("s_waitcnt lgkmcnt(" #n ")" ::: "memory"); \
                       __builtin_amdgcn_sched_barrier(0); }
#define WAIT_VM(n)   { asm volatile("s_waitcnt vmcnt(" #n ")" ::: "memory"); }

// ---------------- weight abs-mean reduction (all 3 weights, blockIdx.y selects) ----------
__global__ void absum_partial(const float4* __restrict__ w1f, const float4* __restrict__ w2f,
                              const float4* __restrict__ w3f, double* __restrict__ part) {
    __shared__ double s[256];
    const int t = threadIdx.x;
    const float4* w = (blockIdx.y == 0) ? w1f : (blockIdx.y == 1) ? w2f : w3f;
    double acc = 0.0;
    const int n4 = NW / 4;
    for (int i = blockIdx.x * 256 + t; i < n4; i += gridDim.x * 256) {
        float4 v = w[i];
        acc += fabs((double)v.x) + fabs((double)v.y) + fabs((double)v.z) + fabs((double)v.w);
    }
    s[t] = acc;
    __syncthreads();
    for (int o = 128; o > 0; o >>= 1) {
        if (t < o) s[t] += s[t + o];
        __syncthreads();
    }
    if (t == 0) part[blockIdx.y * 1024 + blockIdx.x] = s[0];
}

__global__ void finalize_scales(const double* __restrict__ parts, double* __restrict__ scales,
                                int nblocks, double inv_n) {
    const int t = threadIdx.x;
    if (t < 3) {
        const double* p = parts + t * nblocks;
        double s = 0.0;
        for (int i = 0; i < nblocks; ++i) s += p[i];
        double c = fmax(s * inv_n, 1e-5);   // clip(mean|w|, EPS)
        scales[t * 2]     = 1.0 / c;        // quantization scale (fp64)
        scales[t * 2 + 1] = c;              // dequant coeff (fp64)
    }
}

// ---------------- weight ternarize -> int8 {-1,0,1} in FRAGMENT-MAJOR packed layout -------
// Packed layout per weight (NW bytes): for 16-row group c16 (rows = output cols of the
// GEMM), K-tile kt (64 input bytes): 1KB block; lane l=(kg*16+lm) holds row c16*16+lm,
// k bytes kt*64+kg*16 .. +15.  byte_off = (c16*(C/64)+kt)*1024 + lane*16 + (k%16).
// This makes a wave's B-fragment load ONE coalesced dwordx4 at base+lane*16.
__global__ void quant_w_kernel(const float4* __restrict__ w1f, const float4* __restrict__ w2f,
                               const float4* __restrict__ w3f, signed char* __restrict__ twp,
                               const double* __restrict__ scales) {
    const int idx = blockIdx.y;
    const float4* w = (idx == 0) ? w1f : (idx == 1) ? w2f : w3f;
    unsigned char* out = (unsigned char*)(twp + (size_t)idx * NW);
    const int C = (idx == 2) ? H_FF : D_IN;   // row length (input dim)
    const int Ck = C >> 6;                    // K-tiles per row
    const double s = scales[idx * 2];
    const int n4 = NW / 4;
    const int stride = gridDim.x * blockDim.x;
    for (int i = blockIdx.x * blockDim.x + threadIdx.x; i < n4; i += stride) {
        float4 v = w[i];
        int q0 = (int)fmin(fmax(rint((double)v.x * s), -1.0), 1.0);
        int q1 = (int)fmin(fmax(rint((double)v.y * s), -1.0), 1.0);
        int q2 = (int)fmin(fmax(rint((double)v.z * s), -1.0), 1.0);
        int q3 = (int)fmin(fmax(rint((double)v.w * s), -1.0), 1.0);
        const int e = i * 4;
        const int r = e / C;
        const int c = e - r * C;
        const size_t off = ((size_t)((r >> 4) * Ck + (c >> 6))) * 1024
                         + ((((c >> 4) & 3) << 4) + (r & 15)) * 16 + (c & 15);
        *(unsigned int*)(out + off) =
            (unsigned int)((q0 & 255) | ((q1 & 255) << 8) | ((q2 & 255) << 16) | ((q3 & 255) << 24));
    }
}

// ---------------- x: rmsnorm + int8 absmax quant, FP64 stats & rounding ----------------
__global__ void quant_x_kernel(const float* __restrict__ x, signed char* __restrict__ qx,
                               double* __restrict__ cx) {
    __shared__ double ssum[256];
    __shared__ float  smax[256];
    const int token = blockIdx.x;
    const int t = threadIdx.x;
    const float4* xr = (const float4*)(x + (size_t)token * D_IN);
    float4 v0 = xr[t];
    float4 v1 = xr[t + 256];
    double ss = (double)v0.x*v0.x + (double)v0.y*v0.y + (double)v0.z*v0.z + (double)v0.w*v0.w
              + (double)v1.x*v1.x + (double)v1.y*v1.y + (double)v1.z*v1.z + (double)v1.w*v1.w;
    float mx = fmaxf(fmaxf(fmaxf(fabsf(v0.x), fabsf(v0.y)), fmaxf(fabsf(v0.z), fabsf(v0.w))),
                     fmaxf(fmaxf(fabsf(v1.x), fabsf(v1.y)), fmaxf(fabsf(v1.z), fabsf(v1.w))));
    ssum[t] = ss; smax[t] = mx;
    __syncthreads();
    for (int o = 128; o > 0; o >>= 1) {
        if (t < o) { ssum[t] += ssum[t + o]; smax[t] = fmaxf(smax[t], smax[t + o]); }
        __syncthreads();
    }
    const double ms    = ssum[0] * (1.0 / (double)D_IN);
    const double r     = 1.0 / sqrt(ms + 1e-6);
    const double den   = fmax((double)smax[0] * r, 1e-5);   // clip(max|xn|, EPS)
    const double scale = 127.0 / den;
    if (t == 0) cx[token] = den * (1.0 / 127.0);

    int q0 = (int)fmin(fmax(rint(((double)v0.x * r) * scale), -128.0), 127.0);
    int q1 = (int)fmin(fmax(rint(((double)v0.y * r) * scale), -128.0), 127.0);
    int q2 = (int)fmin(fmax(rint(((double)v0.z * r) * scale), -128.0), 127.0);
    int q3 = (int)fmin(fmax(rint(((double)v0.w * r) * scale), -128.0), 127.0);
    int q4 = (int)fmin(fmax(rint(((double)v1.x * r) * scale), -128.0), 127.0);
    int q5 = (int)fmin(fmax(rint(((double)v1.y * r) * scale), -128.0), 127.0);
    int q6 = (int)fmin(fmax(rint(((double)v1.z * r) * scale), -128.0), 127.0);
    int q7 = (int)fmin(fmax(rint(((double)v1.w * r) * scale), -128.0), 127.0);
    unsigned int* qr = (unsigned int*)(qx + (size_t)token * D_IN);
    qr[t]       = (unsigned int)((q0 & 255) | ((q1 & 255) << 8) | ((q2 & 255) << 16) | ((q3 & 255) << 24));
    qr[t + 256] = (unsigned int)((q4 & 255) | ((q5 & 255) << 8) | ((q6 & 255) << 16) | ((q7 & 255) << 24));
}

// ---------------- h: rmsnorm + quant IN-PLACE per token (int8 overlay), FP64 stats --------
__global__ void quant_h_kernel(float* __restrict__ h, double* __restrict__ ch) {
    __shared__ double ssum[256];
    __shared__ float  smax[256];
    const int token = blockIdx.x;
    const int t = threadIdx.x;
    float* hr = h + (size_t)token * H_FF;
    const float2* h2 = (const float2*)hr;
    float2 vals[11];                      // 5632 floats = 2816 float2 = 256*11
    double ss = 0.0;
    float mx = 0.f;
#pragma unroll
    for (int k = 0; k < 11; ++k) {
        float2 v = h2[t + 256 * k];
        vals[k] = v;
        ss += (double)v.x * (double)v.x + (double)v.y * (double)v.y;
        mx = fmaxf(mx, fmaxf(fabsf(v.x), fabsf(v.y)));
    }
    ssum[t] = ss; smax[t] = mx;
    __syncthreads();
    for (int o = 128; o > 0; o >>= 1) {
        if (t < o) { ssum[t] += ssum[t + o]; smax[t] = fmaxf(smax[t], smax[t + o]); }
        __syncthreads();
    }
    const double ms    = ssum[0] * (1.0 / (double)H_FF);
    const double r     = 1.0 / sqrt(ms + 1e-6);
    const double den   = fmax((double)smax[0] * r, 1e-5);
    const double scale = 127.0 / den;
    if (t == 0) ch[token] = den * (1.0 / 127.0);
    unsigned short* qr = (unsigned short*)hr;   // in-place overlay, same token row
#pragma unroll
    for (int k = 0; k < 11; ++k) {
        int a = (int)fmin(fmax(rint(((double)vals[k].x * r) * scale), -128.0), 127.0);
        int b = (int)fmin(fmax(rint(((double)vals[k].y * r) * scale), -128.0), 127.0);
        qr[t + 256 * k] = (unsigned short)((a & 255) | ((b & 255) << 8));
    }
}

// GEMM structure (v8): A in LDS (3 x 16KB, XOR-swizzled, conflict-free); B in REGISTERS
// via coalesced dwordx4 from the fragment-major packed weights, double-buffered, counted
// vmcnt. Removes B from the shared LDS pipe (round-6: LDS 704 + MFMA 653 cyc serialized);
// fixes round-7's uncoalesced-B failure (16 scattered 64B segments -> 1 coalesced 1KB).

// ---------------- fused GEMM1+2, i8 MFMA ---------------------------------------------------
// BM=256, BN=64, BK=64, 512 threads (8 waves: 4M x 2N, 64x32 per wave per gemm), 2 blk/CU.
__global__ void __launch_bounds__(512, 4) gemm12_kernel(
    const signed char* __restrict__ qx,
    const signed char* __restrict__ twp1,  // packed; tw2 = twp1 + NW
    const double* __restrict__ cx,
    const double* __restrict__ scales,
    float* __restrict__ h)
{
    __shared__ __attribute__((aligned(16))) signed char lds[3][16384];   // A only

    const int t = threadIdx.x;
    // XCD-chunked, 2D-blocked traversal: per XCD 704 = 2 bm-halves x 11 bn-groups x (4bm x 8bn)
    // window = 4 bm (2MB A) + 8 bn (2MB packed B) -> both L2-resident.
    {}
    const int xcd = blockIdx.x & 7;
    const int ql  = blockIdx.x >> 3;          // 0..703
    const int hh  = ql / 352;                 // 0..1
    const int tt  = ql - hh * 352;            // 0..351
    const int bm  = xcd * 8 + hh * 4 + ((tt >> 3) & 3);   // 0..63
    const int bn  = (tt >> 5) * 8 + (tt & 7);             // 0..87

    const int srow = t >> 2;           // 0..127
    const int scol = (((t & 3) ^ ((t >> 3) & 3)) << 4);   // inverse-swizzled global slot
    const signed char* gA = qx + (size_t)(bm * 256 + srow) * D_IN + scol;
    const size_t arstep = (size_t)128 * D_IN;
    const int l16 = t * 16;

    const int lane = t & 63;
    const int wv = t >> 6;        // 0..7
    const int wm = wv & 3;        // 4 M-waves (64 rows each)
    const int wn = wv >> 2;       // 2 N-waves (32 cols each per gemm)
    const int lm = lane & 15;
    const int kg = lane >> 4;
    const int koff  = ((kg ^ ((lm >> 1) & 3)) << 4);      // swizzled read slot
    const int abase = (wm * 64 + lm) * 64 + koff;         // + i*1024, i=0..3

    // packed B base: c16 = bn*4 + wn*2 (+j); per-c16 stride = (D_IN/64)*1024 = 32768
    const signed char* gBp = twp1 + (size_t)(bn * 4 + wn * 2) * 32768 + lane * 16;

    const i32x4 izero = {0, 0, 0, 0};
    i32x4 acc1[4][2], acc2[4][2];
#pragma unroll
    for (int i = 0; i < 4; ++i)
#pragma unroll
        for (int j = 0; j < 2; ++j) { acc1[i][j] = izero; acc2[i][j] = izero; }

    i32x4 bA[4], bB[4];   // [0..1]=B1 j=0,1 ; [2..3]=B2 j=0,1

    constexpr int NT = D_IN / 64;   // 32 K-tiles

#define STAGE_A12(buf, kt) { const int go = (kt) * 64;                       \
        async16(gA + go,          &lds[buf][l16]);                           \
        async16(gA + arstep + go, &lds[buf][8192 + l16]); }
#define LOADB12(R, kt) { const int go = (kt) << 10;                          \
        R[0] = *(const i32x4*)(gBp + go);                                    \
        R[1] = *(const i32x4*)(gBp + 32768 + go);                            \
        R[2] = *(const i32x4*)(gBp + NW + go);                               \
        R[3] = *(const i32x4*)(gBp + NW + 32768 + go); }
#define TILE12(kt, RC, RN) {                                                 \
        if ((kt) + 1 < NT) { LOADB12(RN, (kt) + 1); }                        \
        __builtin_amdgcn_sched_barrier(0);                                   \
        if ((kt) + 2 < NT) { STAGE_A12(((kt) + 2) % 3, (kt) + 2); }          \
        __builtin_amdgcn_sched_barrier(0);                                   \
        i32x4 a[4];                                                          \
        _Pragma("unroll") for (int i = 0; i < 4; ++i)                        \
            a[i] = *(const i32x4*)&lds[(kt) % 3][abase + i * 1024];          \
        WAIT_LGKM(0);                                                        \
        __builtin_amdgcn_s_setprio(1);                                       \
        _Pragma("unroll") for (int i = 0; i < 4; ++i) {                      \
            acc1[i][0] = MFMA_I8(a[i], RC[0], acc1[i][0], 0, 0, 0);          \
            acc1[i][1] = MFMA_I8(a[i], RC[1], acc1[i][1], 0, 0, 0);          \
            acc2[i][0] = MFMA_I8(a[i], RC[2], acc2[i][0], 0, 0, 0);          \
            acc2[i][1] = MFMA_I8(a[i], RC[3], acc2[i][1], 0, 0, 0); }        \
        __builtin_amdgcn_s_setprio(0);                                       \
        if ((kt) + 2 < NT) { WAIT_VM(2); } else { WAIT_VM(0); }              \
        sbar(); }

    // prologue FIFO: [A0(2), B0(4), A1(2)] -> WAIT_VM(2) drains A0+B0, keeps A1 in flight
    STAGE_A12(0, 0);
    __builtin_amdgcn_sched_barrier(0);
    LOADB12(bA, 0);
    __builtin_amdgcn_sched_barrier(0);
    STAGE_A12(1, 1);
    WAIT_VM(2);
    sbar();

    for (int kt = 0; kt < NT; kt += 2) {
        TILE12(kt,     bA, bB);
        TILE12(kt + 1, bB, bA);
    }
#undef STAGE_A12
#undef LOADB12
#undef TILE12

    // epilogue: exact int accumulators, FP64 scale products, fp32 silu
    const double cw1 = scales[1];
    const double cw2 = scales[3];
#pragma unroll
    for (int i = 0; i < 4; ++i) {
#pragma unroll
        for (int v = 0; v < 4; ++v) {
            const int row = bm * 256 + wm * 64 + i * 16 + kg * 4 + v;
            const double c  = cx[row];
            const double s1 = c * cw1, s2 = c * cw2;
            float* hp = h + (size_t)row * H_FF + bn * 64 + wn * 32 + lm;
#pragma unroll
            for (int j = 0; j < 2; ++j) {
                float g  = (float)((double)acc1[i][j][v] * s1);
                float u  = (float)((double)acc2[i][j][v] * s2);
                float sg = g / (1.0f + expf(-g));   // silu
                hp[j * 16] = sg * u;
            }
        }
    }
}

// ---------------- GEMM3: i8 h-overlay x packed ternary w3 ---------------------------------
// BM=256, BN=128, BK=64, 512 threads (8 waves: 4M x 2N, 64x64 per wave), 2 blk/CU.
__global__ void __launch_bounds__(512, 4) gemm3_kernel(
    const signed char* __restrict__ qh,
    const signed char* __restrict__ twp3,
    const double* __restrict__ ch,
    const double* __restrict__ scales,
    float* __restrict__ out)
{
    __shared__ __attribute__((aligned(16))) signed char lds[3][16384];   // A only

    const int t = threadIdx.x;
    // per XCD 128 = 2 bm-halves x 4 bn-groups x (4bm x 4bn)
    const int xcd = blockIdx.x & 7;
    const int ql  = blockIdx.x >> 3;          // 0..127
    const int bm  = xcd * 8 + (ql / 64) * 4 + ((ql >> 2) & 3);   // 0..63
    const int bn  = ((ql / 16) & 3) * 4 + (ql & 3);              // 0..15

    const int srow = t >> 2;     // 0..127
    const int scol = (((t & 3) ^ ((t >> 3) & 3)) << 4);
    const size_t qh_stride = (size_t)4 * H_FF;   // bytes per token row (fp32 overlay)
    const signed char* gA = qh + (size_t)(bm * 256 + srow) * qh_stride + scol;
    const size_t arstep = (size_t)128 * qh_stride;
    const int l16 = t * 16;

    const int lane = t & 63;
    const int wv = t >> 6;
    const int wm = wv & 3;        // 4 M-waves (64 rows each)
    const int wn = wv >> 2;       // 2 N-waves (64 cols each)
    const int lm = lane & 15;
    const int kg = lane >> 4;
    const int koff  = ((kg ^ ((lm >> 1) & 3)) << 4);
    const int abase = (wm * 64 + lm) * 64 + koff;          // + i*1024, i=0..3

    // packed B base: c16 = bn*8 + wn*4 (+j); per-c16 stride = (H_FF/64)*1024 = 90112
    const signed char* gBp = twp3 + (size_t)(bn * 8 + wn * 4) * 90112 + lane * 16;

    const i32x4 izero = {0, 0, 0, 0};
    i32x4 acc[4][4];
#pragma unroll
    for (int i = 0; i < 4; ++i)
#pragma unroll
        for (int j = 0; j < 4; ++j) acc[i][j] = izero;

    i32x4 bA[4], bB[4];

    constexpr int NT = H_FF / 64;   // 88 K-tiles

#define STAGE_A3(buf, kt) { const int go = (kt) * 64;                        \
        async16(gA + go,          &lds[buf][l16]);                           \
        async16(gA + arstep + go, &lds[buf][8192 + l16]); }
#define LOADB3(R, kt) { const int go = (kt) << 10;                           \
        R[0] = *(const i32x4*)(gBp + go);                                    \
        R[1] = *(const i32x4*)(gBp + 90112 + go);                            \
        R[2] = *(const i32x4*)(gBp + 180224 + go);                           \
        R[3] = *(const i32x4*)(gBp + 270336 + go); }
#define TILE3(kt, RC, RN) {                                                  \
        if ((kt) + 1 < NT) { LOADB3(RN, (kt) + 1); }                         \
        __builtin_amdgcn_sched_barrier(0);                                   \
        if ((kt) + 2 < NT) { STAGE_A3(((kt) + 2) % 3, (kt) + 2); }           \
        __builtin_amdgcn_sched_barrier(0);                                   \
        i32x4 a[4];                                                          \
        _Pragma("unroll") for (int i = 0; i < 4; ++i)                        \
            a[i] = *(const i32x4*)&lds[(kt) % 3][abase + i * 1024];          \
        WAIT_LGKM(0);                                                        \
        __builtin_amdgcn_s_setprio(1);                                       \
        _Pragma("unroll") for (int i = 0; i < 4; ++i)                        \
        _Pragma("unroll") for (int j = 0; j < 4; ++j)                        \
            acc[i][j] = MFMA_I8(a[i], RC[j], acc[i][j], 0, 0, 0);            \
        __builtin_amdgcn_s_setprio(0);                                       \
        if ((kt) + 2 < NT) { WAIT_VM(2); } else { WAIT_VM(0); }              \
        sbar(); }

    STAGE_A3(0, 0);
    __builtin_amdgcn_sched_barrier(0);
    LOADB3(bA, 0);
    __builtin_amdgcn_sched_barrier(0);
    STAGE_A3(1, 1);
    WAIT_VM(2);
    sbar();

    for (int kt = 0; kt < NT; kt += 2) {
        TILE3(kt,     bA, bB);
        TILE3(kt + 1, bB, bA);
    }
#undef STAGE_A3
#undef LOADB3
#undef TILE3

    const double cw3 = scales[5];
#pragma unroll
    for (int i = 0; i < 4; ++i) {
#pragma unroll
        for (int v = 0; v < 4; ++v) {
            const int row = bm * 256 + wm * 64 + i * 16 + kg * 4 + v;
            const double sc = ch[row] * cw3;
            float* op = out + (size_t)row * D_IN + bn * 128 + wn * 64 + lm;
#pragma unroll
            for (int j = 0; j < 4; ++j) op[j * 16] = (float)((double)acc[i][j][v] * sc);
        }
    }
}

// ---------------- launch ----------------
extern "C" void kernel_launch(void* const* d_in, const int* in_sizes, int n_in,
                              void* d_out, int out_size, void* d_ws, size_t ws_size,
                              hipStream_t stream) {
    const float* x  = (const float*)d_in[0];
    const float* w1 = (const float*)d_in[1];
    const float* w2 = (const float*)d_in[2];
    const float* w3 = (const float*)d_in[3];

    char* ws = (char*)d_ws;
    // workspace layout (bytes, 256-aligned); total = 437,544,960
    double*      scales = (double*)(ws + 0);           // 6 d
    double*      parts  = (double*)(ws + 256);         // 3*1024 d = 24576 B
    double*      cx     = (double*)(ws + 25088);       // 16384 d = 131072 B
    double*      ch     = (double*)(ws + 156416);      // 16384 d = 131072 B
    signed char* twp    = (signed char*)(ws + 287744);      // packed w1|w2|w3, 3*NW B
    float*       hb     = (float*)(ws + 34891520);          // 369,098,752 B (int8 qh overlay)
    signed char* qx     = (signed char*)(ws + 403990528);   // 33,554,432 B

    absum_partial<<<dim3(1024, 3), 256, 0, stream>>>((const float4*)w1, (const float4*)w2,
                                                     (const float4*)w3, parts);
    finalize_scales<<<1, 64, 0, stream>>>(parts, scales, 1024, 1.0 / (double)NW);
    quant_w_kernel<<<dim3(2048, 3), 256, 0, stream>>>((const float4*)w1, (const float4*)w2,
                                                      (const float4*)w3, twp, scales);
    quant_x_kernel<<<M_TOK, 256, 0, stream>>>(x, qx, cx);
    gemm12_kernel<<<5632, 512, 0, stream>>>(qx, twp, cx, scales, hb);
    quant_h_kernel<<<M_TOK, 256, 0, stream>>>(hb, ch);
    gemm3_kernel<<<1024, 512, 0, stream>>>((const signed char*)hb, twp + (size_t)2 * NW,
                                           ch, scales, (float*)d_out);
}